// Round 6
// baseline (1500.253 us; speedup 1.0000x reference)
//
#include <hip/hip_runtime.h>
#include <stdint.h>

// Problem constants (fixed-shape problem)
#define N_NODES 50000
#define N_EDGES 200000
#define N_GRAPH 64
#define F_IN    1536
#define H_DIM   1024
#define C_OUT   80
#define FUSE_D  1024
#define POOL_CHUNK 128
#define MLP1_KC 320   // 2560 / 8 k-chunks
#define MLP1_G  8     // graphs per block
#define SCAN_B  49    // ceil(N_NODES/1024)

typedef unsigned short u16;
typedef short s16x8 __attribute__((ext_vector_type(8)));
typedef float f32x4 __attribute__((ext_vector_type(4)));
typedef unsigned short u16x4 __attribute__((ext_vector_type(4)));
typedef unsigned short u16x8 __attribute__((ext_vector_type(8)));

// ---------- bf16 helpers (bit-level, RNE) ----------
__device__ __forceinline__ float bf2f(u16 u) {
    union { unsigned int i; float f; } v; v.i = ((unsigned int)u) << 16; return v.f;
}
__device__ __forceinline__ u16 f2bf(float f) {
    union { float f; unsigned int i; } v; v.f = f;
    unsigned int x = v.i;
    unsigned int r = (x + 0x7fffu + ((x >> 16) & 1u)) >> 16;
    return (u16)r;
}

// async global->LDS, 16 bytes per lane (lds dest must be linear in lane order)
__device__ __forceinline__ void load_lds16(const void* g, void* l) {
    __builtin_amdgcn_global_load_lds(
        (const __attribute__((address_space(1))) void*)g,
        (__attribute__((address_space(3))) void*)l, 16, 0, 0);
}

// ---------- graph prep kernels ----------
__global__ void k_deg(const int* __restrict__ dst, int* cnt) {
    int e = blockIdx.x * blockDim.x + threadIdx.x;
    if (e < N_EDGES) atomicAdd(&cnt[dst[e]], 1);
}

__global__ void k_cg(const int* __restrict__ batch, int* cG) {
    int i = blockIdx.x * blockDim.x + threadIdx.x;
    if (i < N_NODES) atomicAdd(&cG[batch[i]], 1);
}

// ---------- coalesced 3-kernel scan ----------
__global__ __launch_bounds__(1024) void k_scan_a(const int* __restrict__ cnt, int* __restrict__ bsum) {
    __shared__ int lds[1024];
    int t = threadIdx.x;
    int i = blockIdx.x * 1024 + t;
    lds[t] = (i < N_NODES) ? cnt[i] : 0;
    __syncthreads();
    for (int off = 512; off > 0; off >>= 1) {
        if (t < off) lds[t] += lds[t + off];
        __syncthreads();
    }
    if (t == 0) bsum[blockIdx.x] = lds[0];
}

__global__ __launch_bounds__(64) void k_scan_b(const int* __restrict__ bsum,
                                               int* __restrict__ boff, int* __restrict__ rowptr) {
    int t = threadIdx.x;  // 64 lanes
    int v = (t < SCAN_B) ? bsum[t] : 0;
    for (int off = 1; off < 64; off <<= 1) {
        int u = __shfl_up(v, off);
        if (t >= off) v += u;           // inclusive scan
    }
    if (t < SCAN_B) boff[t] = v - bsum[t];   // exclusive
    if (t == SCAN_B - 1) rowptr[N_NODES] = v;
}

__global__ __launch_bounds__(1024) void k_scan_c(const int* __restrict__ cnt, const int* __restrict__ boff,
                                                 int* __restrict__ rowptr, float* __restrict__ dis) {
    __shared__ int lds[1024];
    int t = threadIdx.x;
    int i = blockIdx.x * 1024 + t;
    int c = (i < N_NODES) ? cnt[i] : 0;
    lds[t] = c;
    __syncthreads();
    for (int off = 1; off < 1024; off <<= 1) {
        int u = (t >= off) ? lds[t - off] : 0;
        __syncthreads();
        lds[t] += u;
        __syncthreads();
    }
    if (i < N_NODES) {
        rowptr[i] = boff[blockIdx.x] + lds[t] - c;   // exclusive prefix
        dis[i] = rsqrtf((float)(c + 1));             // +1 self-loop
    }
}

__global__ void k_fill(const int* __restrict__ src, const int* __restrict__ dst,
                       const int* __restrict__ rowptr, int* cursor, int* col) {
    int e = blockIdx.x * blockDim.x + threadIdx.x;
    if (e < N_EDGES) {
        int d = dst[e];
        int p = atomicAdd(&cursor[d], 1);
        col[rowptr[d] + p] = src[e];
    }
}

// ---------- fp32 -> bf16 cast (vectorized) ----------
__global__ void k_cvt(const float* __restrict__ in, u16* __restrict__ out, long n) {
    long i = (long)blockIdx.x * blockDim.x + threadIdx.x;
    long stride = (long)gridDim.x * blockDim.x;
    for (long v = i * 4; v < n; v += stride * 4) {
        float4 f = *(const float4*)(in + v);
        u16x4 o = { f2bf(f.x), f2bf(f.y), f2bf(f.z), f2bf(f.w) };
        *(u16x4*)(out + v) = o;
    }
}

// W [K x Nn] fp32 -> Wt [Nn x K] bf16 (tiled transpose)
__global__ void k_trn(const float* __restrict__ W, u16* __restrict__ Wt, int K, int Nn) {
    __shared__ float tle[32][33];
    int n0 = blockIdx.x * 32, k0 = blockIdx.y * 32;
    int tx = threadIdx.x, ty = threadIdx.y;  // 32 x 8
    for (int i = ty; i < 32; i += 8)
        tle[i][tx] = W[(size_t)(k0 + i) * Nn + n0 + tx];
    __syncthreads();
    for (int i = ty; i < 32; i += 8)
        Wt[(size_t)(n0 + i) * K + k0 + tx] = f2bf(tle[tx][i]);
}

// ---------- MFMA GEMM: C[Mx1024] = A[MxK] @ Bt[1024xK]^T, all bf16, C bf16 ----------
// 256x256 tile, BK=32, 512 threads = 8 waves (2M x 4N), per-wave 128x64.
//
// DEPTH-3 pipeline (R5 diagnosis: A streams from HBM -- FETCH == |A|; depth-2 at
// BK=64 left ~900cyc misses marginally covered and every overrun stalled all 8
// barrier-locked waves at ~10.5 B/cyc/CU delivered, 5x below m97's 56 B/cyc).
// 4 LDS buffers x 32KB (A 16KB + B 16KB per tile), prefetch 3 tiles ahead:
// 12 loads/thread in flight (96 KB/CU), steady-state s_waitcnt vmcnt(8)
// (peel: 4, then 0). ONE barrier per K-tile: a wave's lgkmcnt(0) precedes its
// MFMAs, so arrival at the next top barrier implies its reads of the previous
// buffer completed; the buffer staged in iter kt is (kt+3)%4 = (kt-1)%4, whose
// readers all passed the top barrier of iter kt. Race-free by program order.
//
// Swizzle (4 slots/row): chunk at (row, slot) holds k-chunk slot ^ ((row>>1)&3);
// reads use slot = qd ^ ((row>>1)&3) -> 16 lanes spread over 8 granule
// positions = 2 lanes/bank-set = free (m136). LDS dest lane-linear (DMA rule).
__global__ __launch_bounds__(512) void gemm_bt(const u16* __restrict__ A,
                                               const u16* __restrict__ Bt,
                                               u16* __restrict__ C,
                                               int M, int Nn, int K) {
    // 4 buffers x 8192 elems (256 rows x 32 k) per matrix
    __shared__ __attribute__((aligned(16))) u16 ldsA[4 * 8192];
    __shared__ __attribute__((aligned(16))) u16 ldsB[4 * 8192];

    int bid = blockIdx.x;
    int swz = (bid & 7) * 98 + (bid >> 3);
    int bN = swz & 3;          // 4 N-tiles (Nn = 1024)
    int bM = swz >> 2;         // 196 M-tiles

    int tid = threadIdx.x;
    int lane = tid & 63, wave = tid >> 6;
    int wm = wave >> 2, wn = wave & 3;     // 2 x 4 wave grid
    int qd = lane >> 4, lo = lane & 15;

    // staging: 1024 chunks of 16B per matrix per tile; 2 A + 2 B per thread.
    // chunk c = r*512+tid -> row c>>2, slot c&3 holds kc = (c&3) ^ ((row>>1)&3).
    const u16* ga[2];
    const u16* gb[2];
#pragma unroll
    for (int r = 0; r < 2; ++r) {
        int c = r * 512 + tid;
        int row = c >> 2;
        int kc = (c & 3) ^ ((row >> 1) & 3);
        int gr = bM * 256 + row;
        if (gr > M - 1) gr = M - 1;        // clamp; garbage rows masked at store
        ga[r] = A + (size_t)gr * K + kc * 8;
        gb[r] = Bt + (size_t)(bN * 256 + row) * K + kc * 8;
    }

    auto stage = [&](int buf) {
        int base = buf * 8192;             // elems
#pragma unroll
        for (int r = 0; r < 2; ++r)
            load_lds16(ga[r], &ldsA[base + (r * 512 + tid) * 8]);
#pragma unroll
        for (int r = 0; r < 2; ++r)
            load_lds16(gb[r], &ldsB[base + (r * 512 + tid) * 8]);
#pragma unroll
        for (int r = 0; r < 2; ++r) { ga[r] += 32; gb[r] += 32; }  // next K-tile
    };

    const int NKT = K >> 5;                // 48 (K=1536) / 32 (K=1024)
    f32x4 acc[8][4] = {};

    // prologue: tiles 0..2 in flight (12 loads/thread)
    stage(0);
    stage(1);
    stage(2);

    // per-lane swizzled k-slot component: qd ^ ((lo>>1)&3)  (row>>1)&3 == (lo>>1)&3
    const int sl = (qd ^ ((lo >> 1) & 3)) * 8;

    for (int kt = 0; kt < NKT; ++kt) {
        int cur = kt & 3;
        if (kt < NKT - 2) {
            asm volatile("s_waitcnt vmcnt(8)" ::: "memory");  // tile kt landed; kt+1,kt+2 in flight
        } else if (kt == NKT - 2) {
            asm volatile("s_waitcnt vmcnt(4)" ::: "memory");
        } else {
            asm volatile("s_waitcnt vmcnt(0)" ::: "memory");
        }
        __builtin_amdgcn_s_barrier();       // tile kt resident for all waves

        const u16* lA = ldsA + cur * 8192;
        const u16* lB = ldsB + cur * 8192;
        s16x8 af[8], bv[4];
#pragma unroll
        for (int mf = 0; mf < 8; ++mf)
            af[mf] = *(const s16x8*)&lA[(wm * 128 + mf * 16 + lo) * 32 + sl];
#pragma unroll
        for (int nf = 0; nf < 4; ++nf)
            bv[nf] = *(const s16x8*)&lB[(wn * 64 + nf * 16 + lo) * 32 + sl];
        asm volatile("s_waitcnt lgkmcnt(0)" ::: "memory");
        __builtin_amdgcn_sched_barrier(0);
        __builtin_amdgcn_s_setprio(1);
#pragma unroll
        for (int mf = 0; mf < 8; ++mf)
#pragma unroll
            for (int nf = 0; nf < 4; ++nf)
                acc[mf][nf] = __builtin_amdgcn_mfma_f32_16x16x32_bf16(
                    af[mf], bv[nf], acc[mf][nf], 0, 0, 0);
        __builtin_amdgcn_s_setprio(0);

        if (kt + 3 < NKT) stage((kt + 3) & 3);  // prefetch; targets buf (kt-1)&3, readers fenced
    }

    // C/D layout: col = lane&15, row = quad*4 + reg  [verified m89/m91]
#pragma unroll
    for (int mf = 0; mf < 8; ++mf) {
        int rowb = bM * 256 + wm * 128 + mf * 16 + qd * 4;
#pragma unroll
        for (int nf = 0; nf < 4; ++nf) {
            int colI = bN * 256 + wn * 64 + nf * 16 + lo;
            f32x4 a = acc[mf][nf];
#pragma unroll
            for (int reg = 0; reg < 4; ++reg) {
                int row = rowb + reg;
                if (row < M) C[(size_t)row * Nn + colI] = f2bf(a[reg]);
            }
        }
    }
}

// ---------- GCN aggregation, wave-per-node: 4 nodes/block, 64 lanes x 16 feats ----
// out[i] = relu(dis_i^2*h[i] + sum_e dis_i*dis_src*h[src] + b)
__global__ __launch_bounds__(256) void k_agg(const u16* __restrict__ hin, u16* __restrict__ hout,
                                             const int* __restrict__ rowptr, const int* __restrict__ col,
                                             const float* __restrict__ dis, const float* __restrict__ bias) {
    int w = threadIdx.x >> 6, lane = threadIdx.x & 63;
    int i = blockIdx.x * 4 + w;            // N_NODES % 4 == 0
    float di = dis[i];
    int beg = rowptr[i], end = rowptr[i + 1];
    const u16* hrow = hin + (size_t)i * H_DIM + lane * 16;
    u16x8 v0 = *(const u16x8*)hrow;
    u16x8 v1 = *(const u16x8*)(hrow + 8);
    float w0 = di * di;
    float acc[16];
#pragma unroll
    for (int j = 0; j < 8; j++) { acc[j] = w0 * bf2f(v0[j]); acc[8 + j] = w0 * bf2f(v1[j]); }
    int e = beg;
    for (; e + 2 <= end; e += 2) {
        int s0 = col[e], s1 = col[e + 1];   // wave-uniform
        float g0 = di * dis[s0], g1 = di * dis[s1];
        const u16* n0 = hin + (size_t)s0 * H_DIM + lane * 16;
        const u16* n1 = hin + (size_t)s1 * H_DIM + lane * 16;
        u16x8 a0 = *(const u16x8*)n0;
        u16x8 a1 = *(const u16x8*)(n0 + 8);
        u16x8 b0 = *(const u16x8*)n1;
        u16x8 b1 = *(const u16x8*)(n1 + 8);
#pragma unroll
        for (int j = 0; j < 8; j++) {
            acc[j]     += g0 * bf2f(a0[j]) + g1 * bf2f(b0[j]);
            acc[8 + j] += g0 * bf2f(a1[j]) + g1 * bf2f(b1[j]);
        }
    }
    if (e < end) {
        int s = col[e];
        float wgt = di * dis[s];
        const u16* nrow = hin + (size_t)s * H_DIM + lane * 16;
        u16x8 u0 = *(const u16x8*)nrow;
        u16x8 u1 = *(const u16x8*)(nrow + 8);
#pragma unroll
        for (int j = 0; j < 8; j++) { acc[j] += wgt * bf2f(u0[j]); acc[8 + j] += wgt * bf2f(u1[j]); }
    }
    const float* bp = bias + lane * 16;
    u16x8 o0, o1;
#pragma unroll
    for (int j = 0; j < 8; j++) {
        o0[j] = f2bf(fmaxf(acc[j] + bp[j], 0.f));
        o1[j] = f2bf(fmaxf(acc[8 + j] + bp[8 + j], 0.f));
    }
    u16* orow = hout + (size_t)i * H_DIM + lane * 16;
    *(u16x8*)orow = o0;
    *(u16x8*)(orow + 8) = o1;
}

// ---------- mean pool: chunked nodes, register segment-accumulate, atomic flush ----------
__global__ __launch_bounds__(256) void k_pool(const u16* __restrict__ h, const int* __restrict__ batch,
                                              float* __restrict__ pooled) {
    int t = threadIdx.x;
    int n0 = blockIdx.x * POOL_CHUNK;
    int n1 = min(n0 + POOL_CHUNK, N_NODES);
    float a0 = 0.f, a1 = 0.f, a2 = 0.f, a3 = 0.f;
    int curg = batch[n0];
    for (int n = n0; n < n1; ++n) {
        int g = batch[n];  // block-uniform
        if (g != curg) {   // uniform branch (rare: ~1-2 per block)
            float* p = &pooled[(size_t)curg * H_DIM + t * 4];
            atomicAdd(p + 0, a0); atomicAdd(p + 1, a1);
            atomicAdd(p + 2, a2); atomicAdd(p + 3, a3);
            a0 = a1 = a2 = a3 = 0.f;
            curg = g;
        }
        u16x4 v = *(const u16x4*)&h[(size_t)n * H_DIM + t * 4];
        a0 += bf2f(v[0]); a1 += bf2f(v[1]); a2 += bf2f(v[2]); a3 += bf2f(v[3]);
    }
    float* p = &pooled[(size_t)curg * H_DIM + t * 4];
    atomicAdd(p + 0, a0); atomicAdd(p + 1, a1);
    atomicAdd(p + 2, a2); atomicAdd(p + 3, a3);
}

// ---------- MLP head layer 1, split-K with atomic accumulation ----------
// grid: (8 gq, 4 jq, 8 kq); block 256. 8 graphs per block (halves fw1 re-reads
// vs 4/block). hid accumulates raw (pre-bias/relu); MLP2 applies bias+relu.
__global__ __launch_bounds__(256) void k_mlp1(const float* __restrict__ gx, const float* __restrict__ pooled,
                                              const int* __restrict__ cG,
                                              const float* __restrict__ fw1, float* __restrict__ hid) {
    __shared__ float comb[MLP1_G * MLP1_KC];
    int gq = blockIdx.x, jq = blockIdx.y, kq = blockIdx.z, t = threadIdx.x;
    int kbeg = kq * MLP1_KC;
    for (int idx = t; idx < MLP1_G * MLP1_KC; idx += 256) {
        int gl = idx / MLP1_KC, kk = idx % MLP1_KC;
        int k = kbeg + kk;
        int g = gq * MLP1_G + gl;
        float v;
        if (k < F_IN) v = gx[(size_t)g * F_IN + k];
        else v = pooled[(size_t)g * H_DIM + (k - F_IN)] / (float)max(cG[g], 1);
        comb[idx] = v;
    }
    __syncthreads();
    int j = jq * 256 + t;
    float a[MLP1_G];
#pragma unroll
    for (int gl = 0; gl < MLP1_G; ++gl) a[gl] = 0.f;
    for (int kk = 0; kk < MLP1_KC; ++kk) {
        float w = fw1[(size_t)(kbeg + kk) * FUSE_D + j];  // coalesced across lanes
#pragma unroll
        for (int gl = 0; gl < MLP1_G; ++gl)
            a[gl] += comb[gl * MLP1_KC + kk] * w;
    }
#pragma unroll
    for (int gl = 0; gl < MLP1_G; ++gl)
        atomicAdd(&hid[(size_t)(gq * MLP1_G + gl) * FUSE_D + j], a[gl]);
}

__global__ __launch_bounds__(128) void k_mlp2(const float* __restrict__ hid, const float* __restrict__ fb1,
                                              const float* __restrict__ fw2,
                                              const float* __restrict__ fb2, float* __restrict__ out) {
    __shared__ float hh[FUSE_D];
    int g = blockIdx.x, t = threadIdx.x;
    for (int idx = t; idx < FUSE_D; idx += 128)
        hh[idx] = fmaxf(hid[(size_t)g * FUSE_D + idx] + fb1[idx], 0.f);  // fused bias+relu
    __syncthreads();
    if (t < C_OUT) {
        float acc = fb2[t];
        for (int k = 0; k < FUSE_D; ++k) acc += hh[k] * fw2[k * C_OUT + t];
        out[g * C_OUT + t] = acc;
    }
}

extern "C" void kernel_launch(void* const* d_in, const int* in_sizes, int n_in,
                              void* d_out, int out_size, void* d_ws, size_t ws_size,
                              hipStream_t stream) {
    (void)in_sizes; (void)n_in; (void)out_size;
    const float* gx    = (const float*)d_in[0];
    const float* x     = (const float*)d_in[1];
    const int*   ei    = (const int*)d_in[2];
    const int*   batch = (const int*)d_in[3];
    const float* W1    = (const float*)d_in[4];
    const float* b1    = (const float*)d_in[5];
    const float* W2    = (const float*)d_in[6];
    const float* b2    = (const float*)d_in[7];
    const float* fw1   = (const float*)d_in[8];
    const float* fb1   = (const float*)d_in[9];
    const float* fw2   = (const float*)d_in[10];
    const float* fb2   = (const float*)d_in[11];
    float* out = (float*)d_out;
    const int* src = ei;
    const int* dst = ei + N_EDGES;

    // workspace layout (~366 MB total, IDENTICAL to last passing layout); zero zone at end
    char* ws = (char*)d_ws;
    size_t off = 0;
    auto alloc = [&](size_t bytes) -> char* {
        char* p = ws + off;
        off += (bytes + 255) & ~(size_t)255;
        return p;
    };
    u16*  xb     = (u16*)alloc((size_t)N_NODES * F_IN * 2);   // reused as h2b
    u16*  h0b    = (u16*)alloc((size_t)N_NODES * H_DIM * 2);  // reused as h3b
    u16*  h1b    = (u16*)alloc((size_t)N_NODES * H_DIM * 2);
    u16*  W1T    = (u16*)alloc((size_t)H_DIM * F_IN * 2);
    u16*  W2T    = (u16*)alloc((size_t)H_DIM * H_DIM * 2);
    float* dis    = (float*)alloc((size_t)N_NODES * 4);
    int* rowptr   = (int*)alloc((size_t)(N_NODES + 1) * 4);
    int* col      = (int*)alloc((size_t)N_EDGES * 4);
    // ---- zero zone start ----
    int* cnt      = (int*)alloc((size_t)N_NODES * 4);
    int* cursor   = (int*)alloc((size_t)N_NODES * 4);
    int* cG       = (int*)alloc(256);
    float* pooled = (float*)alloc((size_t)N_GRAPH * H_DIM * 4);
    float* hid    = (float*)alloc((size_t)N_GRAPH * FUSE_D * 4);
    u16* h2b = xb;
    u16* h3b = h0b;
    // scan scratch aliased into col[] head (col written only later by k_fill)
    int* bsum = col;        // 49 ints
    int* boff = col + 64;   // 49 ints
    (void)ws_size;

    // zero the accumulation zone (ws is poisoned 0xAA before every call)
    size_t zbytes = (size_t)((char*)(hid + N_GRAPH * FUSE_D) - (char*)cnt);
    hipMemsetAsync(cnt, 0, zbytes, stream);

    // graph prep
    k_deg<<<(N_EDGES + 255) / 256, 256, 0, stream>>>(dst, cnt);
    k_cg<<<(N_NODES + 255) / 256, 256, 0, stream>>>(batch, cG);
    k_scan_a<<<SCAN_B, 1024, 0, stream>>>(cnt, bsum);
    k_scan_b<<<1, 64, 0, stream>>>(bsum, boff, rowptr);
    k_scan_c<<<SCAN_B, 1024, 0, stream>>>(cnt, boff, rowptr, dis);
    k_fill<<<(N_EDGES + 255) / 256, 256, 0, stream>>>(src, dst, rowptr, cursor, col);

    // casts / weight transposes
    k_cvt<<<4096, 256, 0, stream>>>(x, xb, (long)N_NODES * F_IN);
    k_trn<<<dim3(H_DIM / 32, F_IN / 32), dim3(32, 8), 0, stream>>>(W1, W1T, F_IN, H_DIM);
    k_trn<<<dim3(H_DIM / 32, H_DIM / 32), dim3(32, 8), 0, stream>>>(W2, W2T, H_DIM, H_DIM);

    // GEMM grid: 196 M-tiles x 4 N-tiles = 784 blocks (784 % 8 == 0 -> clean XCD swizzle)
    const int GEMM_BLOCKS = ((N_NODES + 255) / 256) * (H_DIM / 256);   // 784

    // layer 1
    gemm_bt<<<GEMM_BLOCKS, 512, 0, stream>>>(xb, W1T, h0b, N_NODES, H_DIM, F_IN);
    k_agg<<<N_NODES / 4, 256, 0, stream>>>(h0b, h1b, rowptr, col, dis, b1);
    // layer 2
    gemm_bt<<<GEMM_BLOCKS, 512, 0, stream>>>(h1b, W2T, h2b, N_NODES, H_DIM, H_DIM);
    k_agg<<<N_NODES / 4, 256, 0, stream>>>(h2b, h3b, rowptr, col, dis, b2);

    // pool + head
    k_pool<<<(N_NODES + POOL_CHUNK - 1) / POOL_CHUNK, 256, 0, stream>>>(h3b, batch, pooled);
    k_mlp1<<<dim3(N_GRAPH / MLP1_G, FUSE_D / 256, 8), 256, 0, stream>>>(gx, pooled, cG, fw1, hid);
    k_mlp2<<<N_GRAPH, 128, 0, stream>>>(hid, fb1, fw2, fb2, out);
}

// Round 7
// 1270.929 us; speedup vs baseline: 1.1804x; 1.1804x over previous
//
#include <hip/hip_runtime.h>
#include <stdint.h>

// Problem constants (fixed-shape problem)
#define N_NODES 50000
#define N_EDGES 200000
#define N_GRAPH 64
#define F_IN    1536
#define H_DIM   1024
#define C_OUT   80
#define FUSE_D  1024
#define POOL_CHUNK 128
#define MLP1_KC 320   // 2560 / 8 k-chunks
#define MLP1_G  8     // graphs per block
#define SCAN_B  49    // ceil(N_NODES/1024)

typedef unsigned short u16;
typedef short s16x8 __attribute__((ext_vector_type(8)));
typedef float f32x4 __attribute__((ext_vector_type(4)));
typedef unsigned short u16x4 __attribute__((ext_vector_type(4)));
typedef unsigned short u16x8 __attribute__((ext_vector_type(8)));

// ---------- bf16 helpers (bit-level, RNE) ----------
__device__ __forceinline__ float bf2f(u16 u) {
    union { unsigned int i; float f; } v; v.i = ((unsigned int)u) << 16; return v.f;
}
__device__ __forceinline__ u16 f2bf(float f) {
    union { float f; unsigned int i; } v; v.f = f;
    unsigned int x = v.i;
    unsigned int r = (x + 0x7fffu + ((x >> 16) & 1u)) >> 16;
    return (u16)r;
}

// async global->LDS, 16 bytes per lane (lds dest must be linear in lane order)
__device__ __forceinline__ void load_lds16(const void* g, void* l) {
    __builtin_amdgcn_global_load_lds(
        (const __attribute__((address_space(1))) void*)g,
        (__attribute__((address_space(3))) void*)l, 16, 0, 0);
}

// ---------- graph prep kernels ----------
__global__ void k_deg(const int* __restrict__ dst, int* cnt) {
    int e = blockIdx.x * blockDim.x + threadIdx.x;
    if (e < N_EDGES) atomicAdd(&cnt[dst[e]], 1);
}

// per-graph node counts, wave-segmented (batch is SORTED).
// Old version: 50000 atomicAdds onto 64 ints, same-address within a wave ->
// HW serializes 64 L2 atomics/wave = 235 us (R6 top-5). Now: run-leader lanes
// issue ONE atomicAdd per run (~1-2 runs/wave, ~1.5K atomics total).
__global__ void k_cg(const int* __restrict__ batch, int* cG) {
    int i = blockIdx.x * blockDim.x + threadIdx.x;
    int lane = threadIdx.x & 63;
    int g = (i < N_NODES) ? batch[i] : -1;
    int prev = __shfl_up(g, 1);                 // lane 0: own value
    bool leader = (lane == 0) || (g != prev);
    unsigned long long lm = __ballot(leader);
    if (leader && g >= 0) {
        unsigned long long higher = (lane < 63) ? (lm >> (lane + 1)) : 0ULL;
        int next = higher ? (lane + __ffsll((long long)higher)) : 64;  // next leader lane
        atomicAdd(&cG[g], next - lane);         // run length within this wave
    }
}

// ---------- coalesced 3-kernel scan ----------
__global__ __launch_bounds__(1024) void k_scan_a(const int* __restrict__ cnt, int* __restrict__ bsum) {
    __shared__ int lds[1024];
    int t = threadIdx.x;
    int i = blockIdx.x * 1024 + t;
    lds[t] = (i < N_NODES) ? cnt[i] : 0;
    __syncthreads();
    for (int off = 512; off > 0; off >>= 1) {
        if (t < off) lds[t] += lds[t + off];
        __syncthreads();
    }
    if (t == 0) bsum[blockIdx.x] = lds[0];
}

__global__ __launch_bounds__(64) void k_scan_b(const int* __restrict__ bsum,
                                               int* __restrict__ boff, int* __restrict__ rowptr) {
    int t = threadIdx.x;  // 64 lanes
    int v = (t < SCAN_B) ? bsum[t] : 0;
    for (int off = 1; off < 64; off <<= 1) {
        int u = __shfl_up(v, off);
        if (t >= off) v += u;           // inclusive scan
    }
    if (t < SCAN_B) boff[t] = v - bsum[t];   // exclusive
    if (t == SCAN_B - 1) rowptr[N_NODES] = v;
}

__global__ __launch_bounds__(1024) void k_scan_c(const int* __restrict__ cnt, const int* __restrict__ boff,
                                                 int* __restrict__ rowptr, float* __restrict__ dis) {
    __shared__ int lds[1024];
    int t = threadIdx.x;
    int i = blockIdx.x * 1024 + t;
    int c = (i < N_NODES) ? cnt[i] : 0;
    lds[t] = c;
    __syncthreads();
    for (int off = 1; off < 1024; off <<= 1) {
        int u = (t >= off) ? lds[t - off] : 0;
        __syncthreads();
        lds[t] += u;
        __syncthreads();
    }
    if (i < N_NODES) {
        rowptr[i] = boff[blockIdx.x] + lds[t] - c;   // exclusive prefix
        dis[i] = rsqrtf((float)(c + 1));             // +1 self-loop
    }
}

__global__ void k_fill(const int* __restrict__ src, const int* __restrict__ dst,
                       const int* __restrict__ rowptr, int* cursor, int* col) {
    int e = blockIdx.x * blockDim.x + threadIdx.x;
    if (e < N_EDGES) {
        int d = dst[e];
        int p = atomicAdd(&cursor[d], 1);
        col[rowptr[d] + p] = src[e];
    }
}

// ---------- fp32 -> bf16 cast (vectorized) ----------
__global__ void k_cvt(const float* __restrict__ in, u16* __restrict__ out, long n) {
    long i = (long)blockIdx.x * blockDim.x + threadIdx.x;
    long stride = (long)gridDim.x * blockDim.x;
    for (long v = i * 4; v < n; v += stride * 4) {
        float4 f = *(const float4*)(in + v);
        u16x4 o = { f2bf(f.x), f2bf(f.y), f2bf(f.z), f2bf(f.w) };
        *(u16x4*)(out + v) = o;
    }
}

// W [K x Nn] fp32 -> Wt [Nn x K] bf16 (tiled transpose)
__global__ void k_trn(const float* __restrict__ W, u16* __restrict__ Wt, int K, int Nn) {
    __shared__ float tle[32][33];
    int n0 = blockIdx.x * 32, k0 = blockIdx.y * 32;
    int tx = threadIdx.x, ty = threadIdx.y;  // 32 x 8
    for (int i = ty; i < 32; i += 8)
        tle[i][tx] = W[(size_t)(k0 + i) * Nn + n0 + tx];
    __syncthreads();
    for (int i = ty; i < 32; i += 8)
        Wt[(size_t)(n0 + i) * K + k0 + tx] = f2bf(tle[tx][i]);
}

// ---------- MFMA GEMM: C[Mx1024] = A[MxK] @ Bt[1024xK]^T, all bf16, C bf16 ----------
// 256x256 tile, BK=32, 512 threads = 8 waves (2M x 4N), per-wave 128x64.
// Depth-3 pipeline: 4 LDS buffers, 12 loads/thread in flight, vmcnt(8)/4/0 peel,
// one barrier per K-tile (race-freedom argued inline). Swizzle 4 slots/row.
__global__ __launch_bounds__(512) void gemm_bt(const u16* __restrict__ A,
                                               const u16* __restrict__ Bt,
                                               u16* __restrict__ C,
                                               int M, int Nn, int K) {
    // 4 buffers x 8192 elems (256 rows x 32 k) per matrix
    __shared__ __attribute__((aligned(16))) u16 ldsA[4 * 8192];
    __shared__ __attribute__((aligned(16))) u16 ldsB[4 * 8192];

    int bid = blockIdx.x;
    int swz = (bid & 7) * 98 + (bid >> 3);
    int bN = swz & 3;          // 4 N-tiles (Nn = 1024)
    int bM = swz >> 2;         // 196 M-tiles

    int tid = threadIdx.x;
    int lane = tid & 63, wave = tid >> 6;
    int wm = wave >> 2, wn = wave & 3;     // 2 x 4 wave grid
    int qd = lane >> 4, lo = lane & 15;

    // staging: 1024 chunks of 16B per matrix per tile; 2 A + 2 B per thread.
    // chunk c = r*512+tid -> row c>>2, slot c&3 holds kc = (c&3) ^ ((row>>1)&3).
    const u16* ga[2];
    const u16* gb[2];
#pragma unroll
    for (int r = 0; r < 2; ++r) {
        int c = r * 512 + tid;
        int row = c >> 2;
        int kc = (c & 3) ^ ((row >> 1) & 3);
        int gr = bM * 256 + row;
        if (gr > M - 1) gr = M - 1;        // clamp; garbage rows masked at store
        ga[r] = A + (size_t)gr * K + kc * 8;
        gb[r] = Bt + (size_t)(bN * 256 + row) * K + kc * 8;
    }

    auto stage = [&](int buf) {
        int base = buf * 8192;             // elems
#pragma unroll
        for (int r = 0; r < 2; ++r)
            load_lds16(ga[r], &ldsA[base + (r * 512 + tid) * 8]);
#pragma unroll
        for (int r = 0; r < 2; ++r)
            load_lds16(gb[r], &ldsB[base + (r * 512 + tid) * 8]);
#pragma unroll
        for (int r = 0; r < 2; ++r) { ga[r] += 32; gb[r] += 32; }  // next K-tile
    };

    const int NKT = K >> 5;                // 48 (K=1536) / 32 (K=1024)
    f32x4 acc[8][4] = {};

    // prologue: tiles 0..2 in flight (12 loads/thread)
    stage(0);
    stage(1);
    stage(2);

    // per-lane swizzled k-slot component: qd ^ ((lo>>1)&3)
    const int sl = (qd ^ ((lo >> 1) & 3)) * 8;

    for (int kt = 0; kt < NKT; ++kt) {
        int cur = kt & 3;
        if (kt < NKT - 2) {
            asm volatile("s_waitcnt vmcnt(8)" ::: "memory");  // tile kt landed; kt+1,kt+2 in flight
        } else if (kt == NKT - 2) {
            asm volatile("s_waitcnt vmcnt(4)" ::: "memory");
        } else {
            asm volatile("s_waitcnt vmcnt(0)" ::: "memory");
        }
        __builtin_amdgcn_s_barrier();       // tile kt resident for all waves

        const u16* lA = ldsA + cur * 8192;
        const u16* lB = ldsB + cur * 8192;
        s16x8 af[8], bv[4];
#pragma unroll
        for (int mf = 0; mf < 8; ++mf)
            af[mf] = *(const s16x8*)&lA[(wm * 128 + mf * 16 + lo) * 32 + sl];
#pragma unroll
        for (int nf = 0; nf < 4; ++nf)
            bv[nf] = *(const s16x8*)&lB[(wn * 64 + nf * 16 + lo) * 32 + sl];
        asm volatile("s_waitcnt lgkmcnt(0)" ::: "memory");
        __builtin_amdgcn_sched_barrier(0);
        __builtin_amdgcn_s_setprio(1);
#pragma unroll
        for (int mf = 0; mf < 8; ++mf)
#pragma unroll
            for (int nf = 0; nf < 4; ++nf)
                acc[mf][nf] = __builtin_amdgcn_mfma_f32_16x16x32_bf16(
                    af[mf], bv[nf], acc[mf][nf], 0, 0, 0);
        __builtin_amdgcn_s_setprio(0);

        if (kt + 3 < NKT) stage((kt + 3) & 3);  // prefetch; targets buf (kt-1)&3, readers fenced
    }

    // C/D layout: col = lane&15, row = quad*4 + reg  [verified m89/m91]
#pragma unroll
    for (int mf = 0; mf < 8; ++mf) {
        int rowb = bM * 256 + wm * 128 + mf * 16 + qd * 4;
#pragma unroll
        for (int nf = 0; nf < 4; ++nf) {
            int colI = bN * 256 + wn * 64 + nf * 16 + lo;
            f32x4 a = acc[mf][nf];
#pragma unroll
            for (int reg = 0; reg < 4; ++reg) {
                int row = rowb + reg;
                if (row < M) C[(size_t)row * Nn + colI] = f2bf(a[reg]);
            }
        }
    }
}

// ---------- GCN aggregation, wave-per-node: 4 nodes/block, 64 lanes x 16 feats ----
// out[i] = relu(dis_i^2*h[i] + sum_e dis_i*dis_src*h[src] + b)
__global__ __launch_bounds__(256) void k_agg(const u16* __restrict__ hin, u16* __restrict__ hout,
                                             const int* __restrict__ rowptr, const int* __restrict__ col,
                                             const float* __restrict__ dis, const float* __restrict__ bias) {
    int w = threadIdx.x >> 6, lane = threadIdx.x & 63;
    int i = blockIdx.x * 4 + w;            // N_NODES % 4 == 0
    float di = dis[i];
    int beg = rowptr[i], end = rowptr[i + 1];
    const u16* hrow = hin + (size_t)i * H_DIM + lane * 16;
    u16x8 v0 = *(const u16x8*)hrow;
    u16x8 v1 = *(const u16x8*)(hrow + 8);
    float w0 = di * di;
    float acc[16];
#pragma unroll
    for (int j = 0; j < 8; j++) { acc[j] = w0 * bf2f(v0[j]); acc[8 + j] = w0 * bf2f(v1[j]); }
    int e = beg;
    for (; e + 2 <= end; e += 2) {
        int s0 = col[e], s1 = col[e + 1];   // wave-uniform
        float g0 = di * dis[s0], g1 = di * dis[s1];
        const u16* n0 = hin + (size_t)s0 * H_DIM + lane * 16;
        const u16* n1 = hin + (size_t)s1 * H_DIM + lane * 16;
        u16x8 a0 = *(const u16x8*)n0;
        u16x8 a1 = *(const u16x8*)(n0 + 8);
        u16x8 b0 = *(const u16x8*)n1;
        u16x8 b1 = *(const u16x8*)(n1 + 8);
#pragma unroll
        for (int j = 0; j < 8; j++) {
            acc[j]     += g0 * bf2f(a0[j]) + g1 * bf2f(b0[j]);
            acc[8 + j] += g0 * bf2f(a1[j]) + g1 * bf2f(b1[j]);
        }
    }
    if (e < end) {
        int s = col[e];
        float wgt = di * dis[s];
        const u16* nrow = hin + (size_t)s * H_DIM + lane * 16;
        u16x8 u0 = *(const u16x8*)nrow;
        u16x8 u1 = *(const u16x8*)(nrow + 8);
#pragma unroll
        for (int j = 0; j < 8; j++) { acc[j] += wgt * bf2f(u0[j]); acc[8 + j] += wgt * bf2f(u1[j]); }
    }
    const float* bp = bias + lane * 16;
    u16x8 o0, o1;
#pragma unroll
    for (int j = 0; j < 8; j++) {
        o0[j] = f2bf(fmaxf(acc[j] + bp[j], 0.f));
        o1[j] = f2bf(fmaxf(acc[8 + j] + bp[8 + j], 0.f));
    }
    u16* orow = hout + (size_t)i * H_DIM + lane * 16;
    *(u16x8*)orow = o0;
    *(u16x8*)(orow + 8) = o1;
}

// ---------- mean pool: chunked nodes, register segment-accumulate, atomic flush ----------
__global__ __launch_bounds__(256) void k_pool(const u16* __restrict__ h, const int* __restrict__ batch,
                                              float* __restrict__ pooled) {
    int t = threadIdx.x;
    int n0 = blockIdx.x * POOL_CHUNK;
    int n1 = min(n0 + POOL_CHUNK, N_NODES);
    float a0 = 0.f, a1 = 0.f, a2 = 0.f, a3 = 0.f;
    int curg = batch[n0];
    for (int n = n0; n < n1; ++n) {
        int g = batch[n];  // block-uniform
        if (g != curg) {   // uniform branch (rare: ~1-2 per block)
            float* p = &pooled[(size_t)curg * H_DIM + t * 4];
            atomicAdd(p + 0, a0); atomicAdd(p + 1, a1);
            atomicAdd(p + 2, a2); atomicAdd(p + 3, a3);
            a0 = a1 = a2 = a3 = 0.f;
            curg = g;
        }
        u16x4 v = *(const u16x4*)&h[(size_t)n * H_DIM + t * 4];
        a0 += bf2f(v[0]); a1 += bf2f(v[1]); a2 += bf2f(v[2]); a3 += bf2f(v[3]);
    }
    float* p = &pooled[(size_t)curg * H_DIM + t * 4];
    atomicAdd(p + 0, a0); atomicAdd(p + 1, a1);
    atomicAdd(p + 2, a2); atomicAdd(p + 3, a3);
}

// ---------- MLP head layer 1, split-K with atomic accumulation ----------
// grid: (8 gq, 4 jq, 8 kq); block 256. 8 graphs per block.
__global__ __launch_bounds__(256) void k_mlp1(const float* __restrict__ gx, const float* __restrict__ pooled,
                                              const int* __restrict__ cG,
                                              const float* __restrict__ fw1, float* __restrict__ hid) {
    __shared__ float comb[MLP1_G * MLP1_KC];
    int gq = blockIdx.x, jq = blockIdx.y, kq = blockIdx.z, t = threadIdx.x;
    int kbeg = kq * MLP1_KC;
    for (int idx = t; idx < MLP1_G * MLP1_KC; idx += 256) {
        int gl = idx / MLP1_KC, kk = idx % MLP1_KC;
        int k = kbeg + kk;
        int g = gq * MLP1_G + gl;
        float v;
        if (k < F_IN) v = gx[(size_t)g * F_IN + k];
        else v = pooled[(size_t)g * H_DIM + (k - F_IN)] / (float)max(cG[g], 1);
        comb[idx] = v;
    }
    __syncthreads();
    int j = jq * 256 + t;
    float a[MLP1_G];
#pragma unroll
    for (int gl = 0; gl < MLP1_G; ++gl) a[gl] = 0.f;
    for (int kk = 0; kk < MLP1_KC; ++kk) {
        float w = fw1[(size_t)(kbeg + kk) * FUSE_D + j];  // coalesced across lanes
#pragma unroll
        for (int gl = 0; gl < MLP1_G; ++gl)
            a[gl] += comb[gl * MLP1_KC + kk] * w;
    }
#pragma unroll
    for (int gl = 0; gl < MLP1_G; ++gl)
        atomicAdd(&hid[(size_t)(gq * MLP1_G + gl) * FUSE_D + j], a[gl]);
}

__global__ __launch_bounds__(128) void k_mlp2(const float* __restrict__ hid, const float* __restrict__ fb1,
                                              const float* __restrict__ fw2,
                                              const float* __restrict__ fb2, float* __restrict__ out) {
    __shared__ float hh[FUSE_D];
    int g = blockIdx.x, t = threadIdx.x;
    for (int idx = t; idx < FUSE_D; idx += 128)
        hh[idx] = fmaxf(hid[(size_t)g * FUSE_D + idx] + fb1[idx], 0.f);  // fused bias+relu
    __syncthreads();
    if (t < C_OUT) {
        float acc = fb2[t];
        for (int k = 0; k < FUSE_D; ++k) acc += hh[k] * fw2[k * C_OUT + t];
        out[g * C_OUT + t] = acc;
    }
}

extern "C" void kernel_launch(void* const* d_in, const int* in_sizes, int n_in,
                              void* d_out, int out_size, void* d_ws, size_t ws_size,
                              hipStream_t stream) {
    (void)in_sizes; (void)n_in; (void)out_size;
    const float* gx    = (const float*)d_in[0];
    const float* x     = (const float*)d_in[1];
    const int*   ei    = (const int*)d_in[2];
    const int*   batch = (const int*)d_in[3];
    const float* W1    = (const float*)d_in[4];
    const float* b1    = (const float*)d_in[5];
    const float* W2    = (const float*)d_in[6];
    const float* b2    = (const float*)d_in[7];
    const float* fw1   = (const float*)d_in[8];
    const float* fb1   = (const float*)d_in[9];
    const float* fw2   = (const float*)d_in[10];
    const float* fb2   = (const float*)d_in[11];
    float* out = (float*)d_out;
    const int* src = ei;
    const int* dst = ei + N_EDGES;

    // workspace layout (~366 MB total, IDENTICAL to last passing layout); zero zone at end
    char* ws = (char*)d_ws;
    size_t off = 0;
    auto alloc = [&](size_t bytes) -> char* {
        char* p = ws + off;
        off += (bytes + 255) & ~(size_t)255;
        return p;
    };
    u16*  xb     = (u16*)alloc((size_t)N_NODES * F_IN * 2);   // reused as h2b
    u16*  h0b    = (u16*)alloc((size_t)N_NODES * H_DIM * 2);  // reused as h3b
    u16*  h1b    = (u16*)alloc((size_t)N_NODES * H_DIM * 2);
    u16*  W1T    = (u16*)alloc((size_t)H_DIM * F_IN * 2);
    u16*  W2T    = (u16*)alloc((size_t)H_DIM * H_DIM * 2);
    float* dis    = (float*)alloc((size_t)N_NODES * 4);
    int* rowptr   = (int*)alloc((size_t)(N_NODES + 1) * 4);
    int* col      = (int*)alloc((size_t)N_EDGES * 4);
    // ---- zero zone start ----
    int* cnt      = (int*)alloc((size_t)N_NODES * 4);
    int* cursor   = (int*)alloc((size_t)N_NODES * 4);
    int* cG       = (int*)alloc(256);
    float* pooled = (float*)alloc((size_t)N_GRAPH * H_DIM * 4);
    float* hid    = (float*)alloc((size_t)N_GRAPH * FUSE_D * 4);
    u16* h2b = xb;
    u16* h3b = h0b;
    // scan scratch aliased into col[] head (col written only later by k_fill)
    int* bsum = col;        // 49 ints
    int* boff = col + 64;   // 49 ints
    (void)ws_size;

    // zero the accumulation zone (ws is poisoned 0xAA before every call)
    size_t zbytes = (size_t)((char*)(hid + N_GRAPH * FUSE_D) - (char*)cnt);
    hipMemsetAsync(cnt, 0, zbytes, stream);

    // graph prep
    k_deg<<<(N_EDGES + 255) / 256, 256, 0, stream>>>(dst, cnt);
    k_cg<<<(N_NODES + 255) / 256, 256, 0, stream>>>(batch, cG);
    k_scan_a<<<SCAN_B, 1024, 0, stream>>>(cnt, bsum);
    k_scan_b<<<1, 64, 0, stream>>>(bsum, boff, rowptr);
    k_scan_c<<<SCAN_B, 1024, 0, stream>>>(cnt, boff, rowptr, dis);
    k_fill<<<(N_EDGES + 255) / 256, 256, 0, stream>>>(src, dst, rowptr, cursor, col);

    // casts / weight transposes
    k_cvt<<<4096, 256, 0, stream>>>(x, xb, (long)N_NODES * F_IN);
    k_trn<<<dim3(H_DIM / 32, F_IN / 32), dim3(32, 8), 0, stream>>>(W1, W1T, F_IN, H_DIM);
    k_trn<<<dim3(H_DIM / 32, H_DIM / 32), dim3(32, 8), 0, stream>>>(W2, W2T, H_DIM, H_DIM);

    // GEMM grid: 196 M-tiles x 4 N-tiles = 784 blocks (784 % 8 == 0 -> clean XCD swizzle)
    const int GEMM_BLOCKS = ((N_NODES + 255) / 256) * (H_DIM / 256);   // 784

    // layer 1
    gemm_bt<<<GEMM_BLOCKS, 512, 0, stream>>>(xb, W1T, h0b, N_NODES, H_DIM, F_IN);
    k_agg<<<N_NODES / 4, 256, 0, stream>>>(h0b, h1b, rowptr, col, dis, b1);
    // layer 2
    gemm_bt<<<GEMM_BLOCKS, 512, 0, stream>>>(h1b, W2T, h2b, N_NODES, H_DIM, H_DIM);
    k_agg<<<N_NODES / 4, 256, 0, stream>>>(h2b, h3b, rowptr, col, dis, b2);

    // pool + head
    k_pool<<<(N_NODES + POOL_CHUNK - 1) / POOL_CHUNK, 256, 0, stream>>>(h3b, batch, pooled);
    k_mlp1<<<dim3(N_GRAPH / MLP1_G, FUSE_D / 256, 8), 256, 0, stream>>>(gx, pooled, cG, fw1, hid);
    k_mlp2<<<N_GRAPH, 128, 0, stream>>>(hid, fb1, fw2, fb2, out);
}